// Round 1
// baseline (280.746 us; speedup 1.0000x reference)
//
#include <hip/hip_runtime.h>
#include <math.h>

#define HH 1024
#define WW 1024
#define BB 16
#define ROWS 4
#define NID 32
#define NPX (1ull*BB*HH*WW)

// ws layout (floats): [0..6] global partial sums
//   0: focal_sum  1: inter  2: psum  3: tsum  4: loss_mag_sum  5: dir_sum  6: mask_sum
// [16 .. 16+512)   seg_sum[B][32]
// [528 .. 528+512) seg_cnt[B][32]

__global__ __launch_bounds__(256, 3) void seg_main(
    const float* __restrict__ pred, const float* __restrict__ targ,
    const int* __restrict__ ids, float* __restrict__ acc,
    float* __restrict__ seg_sum, float* __restrict__ seg_cnt) {
  __shared__ float ptile[ROWS + 2][WW];
  __shared__ float ttile[ROWS + 2][WW];
  __shared__ float s_sum[NID];
  __shared__ float s_cnt[NID];
  __shared__ float red[4][8];

  const int tid = threadIdx.x;
  const int blk = blockIdx.x;
  const int b  = blk >> 8;        // 256 row-groups per image (1024/ROWS)
  const int rg = blk & 255;
  const int h0 = rg * ROWS;

  if (tid < NID) { s_sum[tid] = 0.f; s_cnt[tid] = 0.f; }

  const size_t base = (size_t)b * HH * WW;
  const float* pb = pred + base;
  const float* tb = targ + base;
  const int*   ib = ids  + base;

  // stage (ROWS+2) x WW tile of p (clipped sigmoid) and t (clipped)
  for (int it = 0; it < (ROWS + 2) * WW / 256; ++it) {
    int idx = it * 256 + tid;
    int tr  = idx >> 10;          // WW == 1024
    int w   = idx & (WW - 1);
    int hh  = h0 - 1 + tr;
    hh = hh < 0 ? 0 : (hh > HH - 1 ? HH - 1 : hh);
    float x = pb[hh * WW + w];
    float s = 1.f / (1.f + __expf(-x));
    s = fminf(fmaxf(s, 1e-6f), 1.f - 1e-6f);
    ptile[tr][w] = s;
    float t = tb[hh * WW + w];
    ttile[tr][w] = fminf(fmaxf(t, 0.f), 1.f);
  }
  __syncthreads();

  float facc = 0.f, iacc = 0.f, pacc = 0.f, tacc = 0.f;
  float macc = 0.f, dacc = 0.f, kacc = 0.f;

  for (int it = 0; it < ROWS * WW / 256; ++it) {
    int idx = it * 256 + tid;
    int r  = idx >> 10;
    int w  = idx & (WW - 1);
    int tr = r + 1;
    float p = ptile[tr][w];
    float t = ttile[tr][w];

    // focal
    float bce = -(t * __logf(p) + (1.f - t) * log1pf(-p));
    float ptv = (t == 1.f) ? p : 1.f - p;
    float om  = 1.f - ptv;
    float aw  = (t == 1.f) ? 0.25f : 0.75f;
    facc += aw * om * om * bce;

    // dice partials
    iacc += p * t;
    pacc += p;
    tacc += t;

    // sobel (cross-correlation, kornia-normalized /8, replicate pad)
    int wl = (w == 0) ? 0 : w - 1;
    int wr = (w == WW - 1) ? WW - 1 : w + 1;
    float t00 = ttile[tr-1][wl], t01 = ttile[tr-1][w], t02 = ttile[tr-1][wr];
    float t10 = ttile[tr  ][wl],                       t12 = ttile[tr  ][wr];
    float t20 = ttile[tr+1][wl], t21 = ttile[tr+1][w], t22 = ttile[tr+1][wr];
    float tgx = (t02 - t00 + 2.f * (t12 - t10) + t22 - t20) * 0.125f;
    float tgy = (t20 - t00 + 2.f * (t21 - t01) + t22 - t02) * 0.125f;
    float p00 = ptile[tr-1][wl], p01 = ptile[tr-1][w], p02 = ptile[tr-1][wr];
    float p10 = ptile[tr  ][wl],                       p12 = ptile[tr  ][wr];
    float p20 = ptile[tr+1][wl], p21 = ptile[tr+1][w], p22 = ptile[tr+1][wr];
    float pgx = (p02 - p00 + 2.f * (p12 - p10) + p22 - p20) * 0.125f;
    float pgy = (p20 - p00 + 2.f * (p21 - p01) + p22 - p02) * 0.125f;

    float tmag = sqrtf(tgx * tgx + tgy * tgy + 1e-6f);
    float pmag = sqrtf(pgx * pgx + pgy * pgy + 1e-6f);
    float bwv = 1.f + 5.f * tmag;
    float d = (pmag - tmag) * bwv;
    macc += d * d;
    if (tmag > 0.1f) {
      float cosv = (tgx * pgx + tgy * pgy) / (tmag * pmag);
      dacc += 1.f - cosv;
      kacc += 1.f;
    }

    // contrastive segment partials (block is within one image)
    int id = ib[(h0 + r) * WW + w];
    atomicAdd(&s_sum[id], p);
    atomicAdd(&s_cnt[id], 1.f);
  }

  // block-reduce the 7 accumulators
  float v[7] = {facc, iacc, pacc, tacc, macc, dacc, kacc};
  #pragma unroll
  for (int j = 0; j < 7; ++j) {
    float x = v[j];
    #pragma unroll
    for (int off = 32; off > 0; off >>= 1) x += __shfl_down(x, off, 64);
    v[j] = x;
  }
  int wave = tid >> 6;
  int lane = tid & 63;
  if (lane == 0) {
    #pragma unroll
    for (int j = 0; j < 7; ++j) red[wave][j] = v[j];
  }
  __syncthreads();
  if (tid < 7) {
    float s = red[0][tid] + red[1][tid] + red[2][tid] + red[3][tid];
    atomicAdd(&acc[tid], s);
  }
  if (tid < NID) {
    atomicAdd(&seg_sum[b * NID + tid], s_sum[tid]);
    atomicAdd(&seg_cnt[b * NID + tid], s_cnt[tid]);
  }
}

__global__ void seg_final(const float* __restrict__ acc,
                          const float* __restrict__ seg_sum,
                          const float* __restrict__ seg_cnt,
                          float* __restrict__ out) {
  __shared__ float contr[BB];
  int tid = threadIdx.x;              // 256 threads
  int b   = tid >> 4;                 // 16 threads per image
  int l16 = tid & 15;
  if (b < BB) {
    float means[NID];
    bool  val[NID];
    #pragma unroll
    for (int k = 0; k < NID; ++k) {
      float c = seg_cnt[b * NID + k];
      means[k] = seg_sum[b * NID + k] / fmaxf(c, 1.f);
      val[k] = (c > 0.f) && (k > 0);
    }
    float csum = 0.f, np = 0.f;
    int cnt = 0;
    #pragma unroll
    for (int k = 0; k < NID; ++k) {
      #pragma unroll
      for (int l = k + 1; l < NID; ++l) {
        if ((cnt & 15) == l16) {
          if (val[k] && val[l]) {
            csum += __expf(-fabsf(means[k] - means[l]));
            np += 1.f;
          }
        }
        ++cnt;
      }
    }
    #pragma unroll
    for (int off = 1; off < 16; off <<= 1) {
      csum += __shfl_xor(csum, off, 16);
      np   += __shfl_xor(np,   off, 16);
    }
    if (l16 == 0) contr[b] = (np > 0.f) ? csum / fmaxf(np, 1.f) : 0.f;
  }
  __syncthreads();
  if (tid == 0) {
    float c = 0.f;
    for (int b2 = 0; b2 < BB; ++b2) c += contr[b2];
    c /= (float)BB;
    float N = (float)NPX;
    float focal = acc[0] / N;
    float dice  = 1.f - (2.f * acc[1] + 1e-6f) / (acc[2] + acc[3] + 1e-6f);
    float dir   = (acc[6] > 0.f) ? acc[5] / fmaxf(acc[6], 1.f) : 0.f;
    float boundary = acc[4] / N + dir;
    out[0] = focal + dice + 0.5f * boundary + 0.1f * c;
  }
}

extern "C" void kernel_launch(void* const* d_in, const int* in_sizes, int n_in,
                              void* d_out, int out_size, void* d_ws, size_t ws_size,
                              hipStream_t stream) {
  const float* pred = (const float*)d_in[0];
  const float* targ = (const float*)d_in[1];
  const int*   ids  = (const int*)d_in[2];
  float* ws = (float*)d_ws;
  float* acc     = ws;
  float* seg_sum = ws + 16;
  float* seg_cnt = ws + 16 + BB * NID;

  hipMemsetAsync(d_ws, 0, (16 + 2 * BB * NID) * sizeof(float), stream);

  int blocks = BB * (HH / ROWS);   // 4096
  seg_main<<<blocks, 256, 0, stream>>>(pred, targ, ids, acc, seg_sum, seg_cnt);
  seg_final<<<1, 256, 0, stream>>>(acc, seg_sum, seg_cnt, (float*)d_out);
}

// Round 2
// 213.544 us; speedup vs baseline: 1.3147x; 1.3147x over previous
//
#include <hip/hip_runtime.h>
#include <math.h>

#define HH 1024
#define WW 1024
#define BB 16
#define ROWS 4
#define SROWS (ROWS + 2)
#define NID 32
#define NPX (1ull * BB * HH * WW)

// ws layout (floats): [0..6] partial sums
//   0: focal 1: inter 2: psum 3: tsum 4: loss_mag 5: dir_sum 6: mask_sum
// [16..528) seg_sum[B][32], [528..1040) seg_cnt[B][32]

__device__ __forceinline__ float fast_rcp(float x) {
  float r; asm("v_rcp_f32 %0, %1" : "=v"(r) : "v"(x)); return r;
}
__device__ __forceinline__ float fast_rsq(float x) {
  float r; asm("v_rsq_f32 %0, %1" : "=v"(r) : "v"(x)); return r;
}

__global__ __launch_bounds__(256, 3) void seg_main(
    const float* __restrict__ pred, const float* __restrict__ targ,
    const int* __restrict__ ids, float* __restrict__ acc,
    float* __restrict__ seg_sum, float* __restrict__ seg_cnt) {
  __shared__ float ptile[SROWS][WW];
  __shared__ float ttile[SROWS][WW];
  __shared__ float s_sum[NID];
  __shared__ float s_cnt[NID];
  __shared__ float red[4][8];

  const int tid = threadIdx.x;
  const int b  = blockIdx.x >> 8;
  const int rg = blockIdx.x & 255;
  const int h0 = rg * ROWS;
  const int w0 = tid * 4;

  if (tid < NID) { s_sum[tid] = 0.f; s_cnt[tid] = 0.f; }
  __syncthreads();

  const size_t base = (size_t)b * HH * WW;
  const float4* pb4 = (const float4*)(pred + base);
  const float4* tb4 = (const float4*)(targ + base);
  const int4*   ib4 = (const int4*)(ids + base);

  float facc = 0.f, iacc = 0.f, pacc = 0.f, tacc = 0.f;
  float macc = 0.f, dacc = 0.f, kacc = 0.f;

  // ---- staging pass: sigmoid+clip into LDS; fused focal/dice/segment ----
  #pragma unroll
  for (int it = 0; it < SROWS; ++it) {
    int hh = h0 - 1 + it;
    hh = hh < 0 ? 0 : (hh > HH - 1 ? HH - 1 : hh);
    float4 xv = pb4[hh * (WW / 4) + tid];
    float4 tv = tb4[hh * (WW / 4) + tid];
    float xa[4] = {xv.x, xv.y, xv.z, xv.w};
    float ta[4] = {tv.x, tv.y, tv.z, tv.w};
    float pa[4], ca[4];
    #pragma unroll
    for (int j = 0; j < 4; ++j) {
      float e = __expf(-xa[j]);
      float p = fast_rcp(1.f + e);
      p = fminf(fmaxf(p, 1e-6f), 1.f - 1e-6f);
      pa[j] = p;
      ca[j] = fminf(fmaxf(ta[j], 0.f), 1.f);
    }
    float4 pv = {pa[0], pa[1], pa[2], pa[3]};
    float4 cv = {ca[0], ca[1], ca[2], ca[3]};
    *(float4*)&ptile[it][w0] = pv;
    *(float4*)&ttile[it][w0] = cv;

    if (it >= 1 && it <= ROWS) {
      int4 iv = ib4[(h0 + it - 1) * (WW / 4) + tid];
      int ia[4] = {iv.x, iv.y, iv.z, iv.w};
      #pragma unroll
      for (int j = 0; j < 4; ++j) {
        float p = pa[j], t = ca[j];
        float lp = __logf(p);
        float q  = fmaxf(1.f - p, 1e-6f);
        float lq = __logf(q);
        float bce = -(t * lp + (1.f - t) * lq);
        bool one = (t == 1.f);
        float ptv = one ? p : 1.f - p;
        float om  = 1.f - ptv;
        float aw  = one ? 0.25f : 0.75f;
        facc += aw * om * om * bce;
        iacc += p * t;
        pacc += p;
        tacc += t;
        atomicAdd(&s_sum[ia[j]], p);
        atomicAdd(&s_cnt[ia[j]], 1.f);
      }
    }
  }
  __syncthreads();

  // ---- sobel pass: rolling 3 rows in registers, float4 LDS reads ----
  float P[3][6], T[3][6];
  #define LOADROW(tr, dst)                                                  \
    do {                                                                    \
      float4 c = *(const float4*)&ptile[(tr)][w0];                          \
      P[dst][1] = c.x; P[dst][2] = c.y; P[dst][3] = c.z; P[dst][4] = c.w;   \
      P[dst][0] = ptile[(tr)][w0 == 0 ? 0 : w0 - 1];                        \
      P[dst][5] = ptile[(tr)][w0 == WW - 4 ? WW - 1 : w0 + 4];              \
      float4 d = *(const float4*)&ttile[(tr)][w0];                          \
      T[dst][1] = d.x; T[dst][2] = d.y; T[dst][3] = d.z; T[dst][4] = d.w;   \
      T[dst][0] = ttile[(tr)][w0 == 0 ? 0 : w0 - 1];                        \
      T[dst][5] = ttile[(tr)][w0 == WW - 4 ? WW - 1 : w0 + 4];              \
    } while (0)

  LOADROW(0, 0);
  LOADROW(1, 1);
  #pragma unroll
  for (int r = 0; r < ROWS; ++r) {
    const int iA = r % 3, iB = (r + 1) % 3, iC = (r + 2) % 3;
    LOADROW(r + 2, iC);
    #pragma unroll
    for (int j = 0; j < 4; ++j) {
      float t00 = T[iA][j], t01 = T[iA][j + 1], t02 = T[iA][j + 2];
      float t10 = T[iB][j],                     t12 = T[iB][j + 2];
      float t20 = T[iC][j], t21 = T[iC][j + 1], t22 = T[iC][j + 2];
      float tgx = (t02 - t00 + 2.f * (t12 - t10) + t22 - t20) * 0.125f;
      float tgy = (t20 - t00 + 2.f * (t21 - t01) + t22 - t02) * 0.125f;
      float p00 = P[iA][j], p01 = P[iA][j + 1], p02 = P[iA][j + 2];
      float p10 = P[iB][j],                     p12 = P[iB][j + 2];
      float p20 = P[iC][j], p21 = P[iC][j + 1], p22 = P[iC][j + 2];
      float pgx = (p02 - p00 + 2.f * (p12 - p10) + p22 - p20) * 0.125f;
      float pgy = (p20 - p00 + 2.f * (p21 - p01) + p22 - p02) * 0.125f;

      float m2t = tgx * tgx + tgy * tgy + 1e-6f;
      float rst = fast_rsq(m2t);
      float tmag = m2t * rst;
      float m2p = pgx * pgx + pgy * pgy + 1e-6f;
      float rsp = fast_rsq(m2p);
      float pmag = m2p * rsp;

      float bwv = 1.f + 5.f * tmag;
      float d = (pmag - tmag) * bwv;
      macc += d * d;
      if (tmag > 0.1f) {
        float cosv = (tgx * pgx + tgy * pgy) * (rst * rsp);
        dacc += 1.f - cosv;
        kacc += 1.f;
      }
    }
  }
  #undef LOADROW

  // ---- block reduce 7 accumulators ----
  float v[7] = {facc, iacc, pacc, tacc, macc, dacc, kacc};
  #pragma unroll
  for (int j = 0; j < 7; ++j) {
    float x = v[j];
    #pragma unroll
    for (int off = 32; off > 0; off >>= 1) x += __shfl_down(x, off, 64);
    v[j] = x;
  }
  int wave = tid >> 6;
  int lane = tid & 63;
  if (lane == 0) {
    #pragma unroll
    for (int j = 0; j < 7; ++j) red[wave][j] = v[j];
  }
  __syncthreads();
  if (tid < 7) {
    float s = red[0][tid] + red[1][tid] + red[2][tid] + red[3][tid];
    atomicAdd(&acc[tid], s);
  }
  if (tid < NID) {
    atomicAdd(&seg_sum[b * NID + tid], s_sum[tid]);
    atomicAdd(&seg_cnt[b * NID + tid], s_cnt[tid]);
  }
}

__global__ void seg_final(const float* __restrict__ acc,
                          const float* __restrict__ seg_sum,
                          const float* __restrict__ seg_cnt,
                          float* __restrict__ out) {
  __shared__ float contr[BB];
  int tid = threadIdx.x;              // 256 threads
  int b   = tid >> 4;                 // 16 threads per image
  int l16 = tid & 15;
  if (b < BB) {
    float means[NID];
    bool  val[NID];
    #pragma unroll
    for (int k = 0; k < NID; ++k) {
      float c = seg_cnt[b * NID + k];
      means[k] = seg_sum[b * NID + k] / fmaxf(c, 1.f);
      val[k] = (c > 0.f) && (k > 0);
    }
    float csum = 0.f, np = 0.f;
    int cnt = 0;
    #pragma unroll
    for (int k = 0; k < NID; ++k) {
      #pragma unroll
      for (int l = k + 1; l < NID; ++l) {
        if ((cnt & 15) == l16) {
          if (val[k] && val[l]) {
            csum += __expf(-fabsf(means[k] - means[l]));
            np += 1.f;
          }
        }
        ++cnt;
      }
    }
    #pragma unroll
    for (int off = 1; off < 16; off <<= 1) {
      csum += __shfl_xor(csum, off, 16);
      np   += __shfl_xor(np,   off, 16);
    }
    if (l16 == 0) contr[b] = (np > 0.f) ? csum / fmaxf(np, 1.f) : 0.f;
  }
  __syncthreads();
  if (tid == 0) {
    float c = 0.f;
    for (int b2 = 0; b2 < BB; ++b2) c += contr[b2];
    c /= (float)BB;
    float N = (float)NPX;
    float focal = acc[0] / N;
    float dice  = 1.f - (2.f * acc[1] + 1e-6f) / (acc[2] + acc[3] + 1e-6f);
    float dir   = (acc[6] > 0.f) ? acc[5] / fmaxf(acc[6], 1.f) : 0.f;
    float boundary = acc[4] / N + dir;
    out[0] = focal + dice + 0.5f * boundary + 0.1f * c;
  }
}

extern "C" void kernel_launch(void* const* d_in, const int* in_sizes, int n_in,
                              void* d_out, int out_size, void* d_ws, size_t ws_size,
                              hipStream_t stream) {
  const float* pred = (const float*)d_in[0];
  const float* targ = (const float*)d_in[1];
  const int*   ids  = (const int*)d_in[2];
  float* ws = (float*)d_ws;
  float* acc     = ws;
  float* seg_sum = ws + 16;
  float* seg_cnt = ws + 16 + BB * NID;

  hipMemsetAsync(d_ws, 0, (16 + 2 * BB * NID) * sizeof(float), stream);

  int blocks = BB * (HH / ROWS);   // 4096
  seg_main<<<blocks, 256, 0, stream>>>(pred, targ, ids, acc, seg_sum, seg_cnt);
  seg_final<<<1, 256, 0, stream>>>(acc, seg_sum, seg_cnt, (float*)d_out);
}